// Round 3
// baseline (583.963 us; speedup 1.0000x reference)
//
#include <hip/hip_runtime.h>
#include <math.h>

#define N 16384
#define NWORDS 256       // N/64
#define FEAT 512
#define NUM_CATS 65
#define K 25
#define MAX_DETS 1000

// ---------------- ws layout (bytes) ----------------
// keys     : u64[N]            @ 0         (131072)
// rank     : u32[N]            @ 131072    (65536)
// sidx     : u32[N]            @ 196608    (65536)
// sbox     : float4[N]         @ 262144    (262144)
// sarea    : f32[N]            @ 524288    (65536)
// mask     : u64[N*NWORDS]     @ 589824    (33554432)
// idxArr   : i32[32]           @ 34144256  (128)   [31]=count  [30]=ncand
// keepOrig : u8[N]             @ 34144384  (16384)
//
// ncand = #(roi_score >= 0.9). Sort is score-descending, so those items
// occupy sorted positions [0, ncand) and fully determine every keep bit that
// can reach the output (valid requires score>=0.9; suppression & MAX_DETS
// counter only flow down the order). NC = ceil(ncand/64) chunks suffice.
// ncand is computed with the proven store-then-atomicAdd-then-read pattern
// (identical to rank[] init/accumulate), NOT the gather-side atomicMin that
// silently failed in the previous round.

// Sort key: descending by score, ties -> ascending original index.
__global__ void k_build(const float* __restrict__ scores,
                        unsigned long long* __restrict__ keys,
                        unsigned int* __restrict__ rank,
                        int* __restrict__ ncand_slot) {
    int i = blockIdx.x * 256 + threadIdx.x;
    keys[i] = ((unsigned long long)__float_as_uint(scores[i]) << 32) |
              (unsigned long long)(0xFFFFFFFFu - (unsigned)i);
    rank[i] = 0u;
    if (i == 0) *ncand_slot = 0;   // counted up by k_rank
}

// rank[i] = #{ j : key[j] > key[i] }  (keys distinct -> permutation)
// y==0 slice also counts scores >= 0.9 into ncand_slot.
__global__ void k_rank(const unsigned long long* __restrict__ keys,
                       const float* __restrict__ scores,
                       unsigned int* __restrict__ rank,
                       int* __restrict__ ncand_slot) {
    __shared__ unsigned long long lk[2048];
    int i = blockIdx.x * 256 + threadIdx.x;
    unsigned long long my = keys[i];
    int j0 = blockIdx.y * 2048;
    for (int t = threadIdx.x; t < 2048; t += 256) lk[t] = keys[j0 + t];
    __syncthreads();
    unsigned int cnt = 0;
#pragma unroll 8
    for (int t = 0; t < 2048; ++t) cnt += (lk[t] > my) ? 1u : 0u;
    atomicAdd(&rank[i], cnt);
    if (blockIdx.y == 0) {
        bool hi = scores[i] >= 0.9f;
        unsigned long long bal = __ballot(hi);
        if ((threadIdx.x & 63) == 0)
            atomicAdd(ncand_slot, (int)__popcll(bal));
    }
}

// Scatter boxes directly into sorted order (fuses old k_scatter+k_gather):
// coalesced reads of rank/boxes, scattered writes by rank.
__global__ void k_scatter(const unsigned int* __restrict__ rank,
                          const float* __restrict__ det_boxes,
                          unsigned int* __restrict__ sidx,
                          float4* __restrict__ sbox,
                          float* __restrict__ sarea) {
    int i = blockIdx.x * 256 + threadIdx.x;
    unsigned int r = rank[i];
    sidx[r] = (unsigned int)i;
    float4 b = ((const float4*)det_boxes)[i];   // [y1,x1,y2,x2]
    sbox[r] = b;
    sarea[r] = (b.w - b.y) * (b.z - b.x);       // (x2-x1)*(y2-y1)
}

// Upper-triangular (block-wise) IoU>0.6 bit matrix, candidate chunks only.
// Persistent-tile kernel: fixed 1024-block grid; tiles enumerated
// t = cb*(cb+1)/2 + rb (rb<=cb<NC). mask[row*256+cb] bit j set iff
// IoU(row, cb*64+j) > 0.6 and col > row.
__global__ void k_mask(const float4* __restrict__ sbox,
                       const float* __restrict__ sarea,
                       const int* __restrict__ ncand_slot,
                       unsigned long long* __restrict__ mask) {
    int ncand = *ncand_slot;
    if (ncand < 0) ncand = 0;
    if (ncand > N) ncand = N;
    int NC = (ncand + 63) >> 6;
    int total = NC * (NC + 1) / 2;
    __shared__ float4 cbox[64];
    __shared__ float carea[64];
    int t = threadIdx.x;
    for (int tile = blockIdx.x; tile < total; tile += gridDim.x) {
        int cb = (int)((sqrtf(8.0f * (float)tile + 1.0f) - 1.0f) * 0.5f);
        while ((cb + 1) * (cb + 2) / 2 <= tile) ++cb;
        while (cb * (cb + 1) / 2 > tile) --cb;
        int rb = tile - cb * (cb + 1) / 2;

        __syncthreads();                       // protect cbox reuse
        int col0 = cb * 64;
        cbox[t] = sbox[col0 + t];
        carea[t] = sarea[col0 + t];
        __syncthreads();
        int row = rb * 64 + t;
        float4 r = sbox[row];
        float ra = sarea[row];
        unsigned long long bits = 0ull;
        for (int j = 0; j < 64; ++j) {
            int col = col0 + j;
            if (col > row) {
                float4 cbx = cbox[j];
                float iw = fminf(r.w, cbx.w) - fmaxf(r.y, cbx.y);  // x overlap
                iw = fmaxf(iw, 0.0f);
                float ih = fminf(r.z, cbx.z) - fmaxf(r.x, cbx.x);  // y overlap
                ih = fmaxf(ih, 0.0f);
                float inter = iw * ih;
                float iou = inter / (ra + carea[j] - inter + 1e-12f);
                if (iou > 0.6f) bits |= (1ull << j);
            }
        }
        mask[(size_t)row * NWORDS + cb] = bits;
    }
}

// Single-wave greedy scan. Suppression state in LDS supp[256] (single wave,
// no barriers; distinct word per lane; broadcast read of supp[c]).
// Phase A: in-chunk greedy decisions via LDS-broadcast diag reads.
// Phase B: windowed [c+1, NC) x 16-row-batched COALESCED suppression loads —
// lane L reads word c+1+L of each kept row (8 B/lane contiguous), 16 rows in
// flight per round trip.
__global__ void __launch_bounds__(64, 1)
k_scan(const unsigned long long* __restrict__ mask,
       const unsigned int* __restrict__ sidx,
       const int* __restrict__ ncand_slot,
       unsigned char* __restrict__ keepOrig) {
    __shared__ unsigned long long keepw_arr[NWORDS];
    __shared__ unsigned long long supp[NWORDS];
    __shared__ unsigned long long diag[64 * 64];   // 32 KB: diag words, chunks<64
    int lane = threadIdx.x;                        // 64 threads = 1 wave

    int ncand = *ncand_slot;
    if (ncand < 0) ncand = 0;
    if (ncand > N) ncand = N;
    int NC = (ncand + 63) >> 6;

    for (int i2 = lane; i2 < NWORDS; i2 += 64) {
        keepw_arr[i2] = 0ull;
        supp[i2] = 0ull;
    }

    // preload diagonal words for chunks < min(NC,64); independent scattered
    // loads, pipelined by the compiler.
    int NCl = NC < 64 ? NC : 64;
    for (int t = lane; t < NCl * 64; t += 64)
        diag[t] = mask[(size_t)t * NWORDS + (t >> 6)];

    int cnt = 0;                                   // uniform across lanes
    unsigned long long dnext = 0ull;               // one-ahead diag prefetch, c>=64

    for (int c = 0; c < NC; ++c) {
        if (cnt >= MAX_DETS) break;                // keepw_arr pre-zeroed

        unsigned long long dcur = dnext;
        if (c + 1 >= 64 && c + 1 < NC)             // prefetch next diag (rare path)
            dnext = mask[(size_t)((c + 1) * 64 + lane) * NWORDS + (c + 1)];

        unsigned long long alive = ~supp[c];       // broadcast LDS read, uniform

        // ---- phase A: greedy keep decisions ----
        unsigned long long keepw = 0ull;
        while (alive && cnt < MAX_DETS) {
            int t = __ffsll((long long)alive) - 1;    // lowest alive bit -> kept
            keepw |= (1ull << t);
            ++cnt;
            unsigned long long dt = (c < 64) ? diag[c * 64 + t]   // LDS broadcast
                                             : __shfl(dcur, t, 64);
            alive &= ~(dt | (1ull << t));
        }
        if (lane == 0) keepw_arr[c] = keepw;

        // ---- phase B: windowed coalesced suppression OR ----
        if (cnt < MAX_DETS && keepw != 0ull) {
            const unsigned long long* rowp = mask + (size_t)(c * 64) * NWORDS;
            for (int wb = c + 1; wb < NC; wb += 64) {
                int wi = wb + lane;                // word this lane owns
                bool act = (wi < NC);
                unsigned long long acc = 0ull;
                unsigned long long w = keepw;
                while (w) {
#define SLOT(i)                                                           \
                    unsigned long long A##i = 0ull;                       \
                    if (w) {                                              \
                        int t = __ffsll((long long)w) - 1;                \
                        w &= w - 1ull;                                    \
                        if (act) A##i = rowp[(size_t)t * NWORDS + wi];    \
                    }
                    SLOT(0) SLOT(1) SLOT(2) SLOT(3)
                    SLOT(4) SLOT(5) SLOT(6) SLOT(7)
                    SLOT(8) SLOT(9) SLOT(10) SLOT(11)
                    SLOT(12) SLOT(13) SLOT(14) SLOT(15)
#undef SLOT
                    acc |= A0 | A1 | A2 | A3 | A4 | A5 | A6 | A7
                         | A8 | A9 | A10 | A11 | A12 | A13 | A14 | A15;
                }
                if (act) supp[wi] |= acc;
            }
        }
    }

    // scatter keep bits back to original index order (chunks >= NC are zero;
    // sub-0.9 items may carry stale zeros only — masked by score in k_select)
    for (int i2 = lane; i2 < N; i2 += 64) {
        unsigned char b = (unsigned char)((keepw_arr[i2 >> 6] >> (i2 & 63)) & 1ull);
        keepOrig[sidx[i2]] = b;
    }
}

// valid = keep & ~all(roi_boxes==0) & (score>=0.9) & (rescaled area>220);
// collect first K valid in original-index order + total count.
__global__ void k_select(const unsigned char* __restrict__ keepOrig,
                         const float* __restrict__ roi_boxes,
                         const float* __restrict__ roi_scores,
                         const float* __restrict__ det_boxes,
                         const float* __restrict__ info,
                         int* __restrict__ idxArr) {
    __shared__ int wcnt[16];
    int tid = threadIdx.x;
    if (tid < K) idxArr[tid] = 0;
    __syncthreads();
    float sy = info[4], sx = info[5];
    int base = 0;
    for (int ch = 0; ch < 16; ++ch) {
        int i = ch * 1024 + tid;
        bool keep = keepOrig[i] != 0;
        float4 rb = ((const float4*)roi_boxes)[i];
        bool nz = !((rb.x == 0.0f) && (rb.y == 0.0f) && (rb.z == 0.0f) && (rb.w == 0.0f));
        bool sc = roi_scores[i] >= 0.9f;
        float4 db = ((const float4*)det_boxes)[i];
        float r0 = db.x / sy, r1 = db.y / sx, r2 = db.z / sy, r3 = db.w / sx;
        bool big = ((r2 - r0) * (r3 - r1)) > 220.0f;
        bool valid = keep && nz && sc && big;
        unsigned long long bal = __ballot(valid);
        int wv = tid >> 6, lane = tid & 63;
        if (lane == 0) wcnt[wv] = (int)__popcll(bal);
        __syncthreads();
        int pre = 0, tot = 0;
        for (int w = 0; w < 16; ++w) { int cc = wcnt[w]; tot += cc; if (w < wv) pre += cc; }
        int rk = base + pre + (int)__popcll(bal & ((1ull << lane) - 1ull));
        if (valid && rk < K) idxArr[rk] = i;
        base += tot;
        __syncthreads();
    }
    if (tid == 0) idxArr[31] = base;   // full valid count
}

// 25x65 classification, argmax/fg, stable descending sort, epilogue writes.
__global__ void k_classify(const float* __restrict__ vis,
                           const float* __restrict__ tf,
                           const float* __restrict__ det_boxes,
                           const float* __restrict__ info,
                           const int* __restrict__ idxArr,
                           float* __restrict__ out) {
    __shared__ float feat[K * FEAT];       // 51200 B
    __shared__ float sc[K * NUM_CATS];     // 6500 B
    __shared__ float keyL[K];
    __shared__ int fgL[K];
    __shared__ int ordL[K];
    int tid = threadIdx.x;
    int count = idxArr[31];
    int mincount = count < K ? count : K;

    for (int r = 0; r < K; ++r) {
        int o = idxArr[r];
        for (int e = tid; e < FEAT; e += 256)
            feat[r * FEAT + e] = vis[(size_t)o * FEAT + e];
    }
    __syncthreads();

    for (int p = tid; p < K * NUM_CATS; p += 256) {
        int r = p / NUM_CATS, c = p % NUM_CATS;
        const float* fr = &feat[r * FEAT];
        const float* tr = &tf[(size_t)c * FEAT];
        float s = 0.0f;
#pragma unroll 8
        for (int e = 0; e < FEAT; ++e) s += fr[e] * tr[e];
        sc[p] = s;
    }
    __syncthreads();

    if (tid < K) {
        float mv = sc[tid * NUM_CATS];
        int ma = 0;
        for (int c = 1; c < NUM_CATS; ++c) {
            float v = sc[tid * NUM_CATS + c];
            if (v > mv) { mv = v; ma = c; }     // first-max (jnp.argmax)
        }
        int fg = (tid < mincount) && (ma != 0);
        fgL[tid] = fg;
        keyL[tid] = fg ? mv : -INFINITY;
    }
    __syncthreads();

    if (tid == 0) {                 // stable selection sort, descending
        unsigned used = 0;
        for (int p = 0; p < K; ++p) {
            int bk = -1; float bv = 0.0f;
            for (int k2 = 0; k2 < K; ++k2) {
                if (used & (1u << k2)) continue;
                if (bk < 0 || keyL[k2] > bv) { bk = k2; bv = keyL[k2]; }
            }
            ordL[p] = bk;
            used |= (1u << bk);
        }
    }
    __syncthreads();

    float sy = info[4], sx = info[5];
    // scores: [0 .. 1599]
    for (int p = tid; p < K * (NUM_CATS - 1); p += 256) {
        int q = p >> 6, cc = p & 63;
        int src = ordL[q];
        out[p] = fgL[src] ? sc[src * NUM_CATS + cc + 1] : 0.0f;
    }
    // bboxes: [1600 .. 1699]  processed = [xmin, ymin, xmax, ymax]
    for (int p = tid; p < K * 4; p += 256) {
        int q = p >> 2, e = p & 3;
        int src = ordL[q];
        float v = 0.0f;
        if (fgL[src]) {
            int o = idxArr[src];
            float b0 = det_boxes[o * 4 + 0] / sy;   // ymin
            float b1 = det_boxes[o * 4 + 1] / sx;   // xmin
            float b2 = det_boxes[o * 4 + 2] / sy;   // ymax
            float b3 = det_boxes[o * 4 + 3] / sx;   // xmax
            v = (e == 0) ? b1 : (e == 1) ? b0 : (e == 2) ? b3 : b2;
        }
        out[1600 + p] = v;
    }
    // mask: [1700 .. 1724]
    if (tid < K) out[1700 + tid] = fgL[ordL[tid]] ? 1.0f : 0.0f;
}

extern "C" void kernel_launch(void* const* d_in, const int* in_sizes, int n_in,
                              void* d_out, int out_size, void* d_ws, size_t ws_size,
                              hipStream_t stream) {
    const float* roi_boxes  = (const float*)d_in[0];
    const float* roi_scores = (const float*)d_in[1];
    const float* det_boxes  = (const float*)d_in[2];
    // d_in[3] detection_masks: unused by reference
    const float* vis        = (const float*)d_in[4];
    const float* info       = (const float*)d_in[5];
    const float* tf         = (const float*)d_in[6];

    char* ws = (char*)d_ws;
    unsigned long long* keys = (unsigned long long*)(ws + 0);
    unsigned int* rank       = (unsigned int*)(ws + 131072);
    unsigned int* sidx       = (unsigned int*)(ws + 196608);
    float4* sbox             = (float4*)(ws + 262144);
    float* sarea             = (float*)(ws + 524288);
    unsigned long long* mask = (unsigned long long*)(ws + 589824);
    int* idxArr              = (int*)(ws + 34144256);
    unsigned char* keepOrig  = (unsigned char*)(ws + 34144384);
    int* ncand_slot          = idxArr + 30;   // unused slot of idxArr

    k_build<<<64, 256, 0, stream>>>(roi_scores, keys, rank, ncand_slot);
    k_rank<<<dim3(64, 8), 256, 0, stream>>>(keys, roi_scores, rank, ncand_slot);
    k_scatter<<<64, 256, 0, stream>>>(rank, det_boxes, sidx, sbox, sarea);
    k_mask<<<1024, 64, 0, stream>>>(sbox, sarea, ncand_slot, mask);
    k_scan<<<1, 64, 0, stream>>>(mask, sidx, ncand_slot, keepOrig);
    k_select<<<1, 1024, 0, stream>>>(keepOrig, roi_boxes, roi_scores, det_boxes, info, idxArr);
    k_classify<<<1, 256, 0, stream>>>(vis, tf, det_boxes, info, idxArr, (float*)d_out);
}

// Round 4
// 407.701 us; speedup vs baseline: 1.4323x; 1.4323x over previous
//
#include <hip/hip_runtime.h>
#include <math.h>

#define N 16384
#define NWORDS 256       // N/64
#define FEAT 512
#define NUM_CATS 65
#define K 25
#define MAX_DETS 1000

// ---------------- ws layout (bytes) ----------------
// keys     : u64[N]            @ 0         (131072)
// rank     : u32[N]            @ 131072    (65536)
// (unused) : u32[N]            @ 196608    (65536)
// sbox     : float4[N]         @ 262144    (262144)
// sarea    : f32[N]            @ 524288    (65536)
// mask     : u64[N*NWORDS]     @ 589824    (33554432)
// idxArr   : i32[32]           @ 34144256  (128)   [30]=ncand
//
// ncand = #(roi_score >= 0.9). Sort is score-descending; suppression and the
// MAX_DETS counter only flow down the order, and valid requires score>=0.9,
// so the first NC = ceil(ncand/64) sorted chunks fully determine the output.
//
// Bottleneck history: phase A of the greedy scan is a ~1030-iteration serial
// dependent chain; LDS/shfl broadcast inside it cost ~590 cy/item across
// three structurally different versions. This version uses v_readlane
// (register crossbar, no LDS) + readfirstlane-anchored scalar state, and
// fuses scan+select+classify into one kernel (no keepOrig round trip).

// Sort key: descending by score, ties -> ascending original index.
__global__ void k_build(const float* __restrict__ scores,
                        unsigned long long* __restrict__ keys,
                        unsigned int* __restrict__ rank,
                        int* __restrict__ ncand_slot) {
    int i = blockIdx.x * 256 + threadIdx.x;
    keys[i] = ((unsigned long long)__float_as_uint(scores[i]) << 32) |
              (unsigned long long)(0xFFFFFFFFu - (unsigned)i);
    rank[i] = 0u;
    if (i == 0) *ncand_slot = 0;   // counted up by k_rank
}

// rank[i] = #{ j : key[j] > key[i] }  (keys distinct -> permutation)
// y==0 slice also counts scores >= 0.9 into ncand_slot (proven pattern).
__global__ void k_rank(const unsigned long long* __restrict__ keys,
                       const float* __restrict__ scores,
                       unsigned int* __restrict__ rank,
                       int* __restrict__ ncand_slot) {
    __shared__ unsigned long long lk[2048];
    int i = blockIdx.x * 256 + threadIdx.x;
    unsigned long long my = keys[i];
    int j0 = blockIdx.y * 2048;
    for (int t = threadIdx.x; t < 2048; t += 256) lk[t] = keys[j0 + t];
    __syncthreads();
    unsigned int cnt = 0;
#pragma unroll 8
    for (int t = 0; t < 2048; ++t) cnt += (lk[t] > my) ? 1u : 0u;
    atomicAdd(&rank[i], cnt);
    if (blockIdx.y == 0) {
        bool hi = scores[i] >= 0.9f;
        unsigned long long bal = __ballot(hi);
        if ((threadIdx.x & 63) == 0)
            atomicAdd(ncand_slot, (int)__popcll(bal));
    }
}

// Scatter boxes into sorted order; precompute areas (exact ref formula).
__global__ void k_scatter(const unsigned int* __restrict__ rank,
                          const float* __restrict__ det_boxes,
                          float4* __restrict__ sbox,
                          float* __restrict__ sarea) {
    int i = blockIdx.x * 256 + threadIdx.x;
    unsigned int r = rank[i];
    float4 b = ((const float4*)det_boxes)[i];   // [y1,x1,y2,x2]
    sbox[r] = b;
    sarea[r] = (b.w - b.y) * (b.z - b.x);       // (x2-x1)*(y2-y1)
}

// Upper-triangular (block-wise) IoU>0.6 bit matrix, candidate chunks only.
// Persistent-tile kernel, fixed 1024-block grid.
__global__ void k_mask(const float4* __restrict__ sbox,
                       const float* __restrict__ sarea,
                       const int* __restrict__ ncand_slot,
                       unsigned long long* __restrict__ mask) {
    int ncand = *ncand_slot;
    if (ncand < 0) ncand = 0;
    if (ncand > N) ncand = N;
    int NC = (ncand + 63) >> 6;
    int total = NC * (NC + 1) / 2;
    __shared__ float4 cbox[64];
    __shared__ float carea[64];
    int t = threadIdx.x;
    for (int tile = blockIdx.x; tile < total; tile += gridDim.x) {
        int cb = (int)((sqrtf(8.0f * (float)tile + 1.0f) - 1.0f) * 0.5f);
        while ((cb + 1) * (cb + 2) / 2 <= tile) ++cb;
        while (cb * (cb + 1) / 2 > tile) --cb;
        int rb = tile - cb * (cb + 1) / 2;

        __syncthreads();                       // protect cbox reuse
        int col0 = cb * 64;
        cbox[t] = sbox[col0 + t];
        carea[t] = sarea[col0 + t];
        __syncthreads();
        int row = rb * 64 + t;
        float4 r = sbox[row];
        float ra = sarea[row];
        unsigned long long bits = 0ull;
        for (int j = 0; j < 64; ++j) {
            int col = col0 + j;
            if (col > row) {
                float4 cbx = cbox[j];
                float iw = fminf(r.w, cbx.w) - fmaxf(r.y, cbx.y);  // x overlap
                iw = fmaxf(iw, 0.0f);
                float ih = fminf(r.z, cbx.z) - fmaxf(r.x, cbx.x);  // y overlap
                ih = fmaxf(ih, 0.0f);
                float inter = iw * ih;
                float iou = inter / (ra + carea[j] - inter + 1e-12f);
                if (iou > 0.6f) bits |= (1ull << j);
            }
        }
        mask[(size_t)row * NWORDS + cb] = bits;
    }
}

// Fused tail: wave 0 runs the greedy scan (readlane-based, scalar-anchored);
// then all 1024 threads do select (via rank[] + LDS keep bits) and classify.
__global__ void __launch_bounds__(1024, 1)
k_tail(const unsigned long long* __restrict__ mask,
       const unsigned int* __restrict__ rank,
       const int* __restrict__ ncand_slot,
       const float* __restrict__ roi_boxes,
       const float* __restrict__ roi_scores,
       const float* __restrict__ det_boxes,
       const float* __restrict__ info,
       const float* __restrict__ vis,
       const float* __restrict__ tf,
       float* __restrict__ out) {
    __shared__ unsigned long long keepw_arr[NWORDS];   // 2 KB
    __shared__ unsigned long long supp[NWORDS];        // 2 KB
    __shared__ float feat[K * FEAT];                   // 50 KB
    __shared__ float scL[K * NUM_CATS];                // 6.5 KB
    __shared__ float keyL[K];
    __shared__ int fgL[K];
    __shared__ int ordL[K];
    __shared__ int idxL[K];
    __shared__ int wcnt[16];
    __shared__ int countL;
    int tid = threadIdx.x;

    if (tid < K) idxL[tid] = 0;

    // =================== phase 1: greedy NMS scan (wave 0) ===================
    if (tid < 64) {
        int lane = tid;
        for (int i2 = lane; i2 < NWORDS; i2 += 64) {
            keepw_arr[i2] = 0ull;
            supp[i2] = 0ull;
        }
        int ncand = *ncand_slot;
        if (ncand < 0) ncand = 0;
        if (ncand > N) ncand = N;
        int NC = (ncand + 63) >> 6;

        int cnt = 0;
        unsigned long long dnext = 0ull;
        if (NC > 0) dnext = mask[(size_t)lane * NWORDS];   // chunk 0 diag word

        for (int c = 0; c < NC; ++c) {
            if (cnt >= MAX_DETS) break;                    // keepw_arr pre-zeroed

            unsigned long long dcur = dnext;               // row lane's in-chunk word
            if (c + 1 < NC)                                // one-ahead prefetch
                dnext = mask[(size_t)((c + 1) * 64 + lane) * NWORDS + (c + 1)];
            unsigned int dlo = (unsigned int)dcur;
            unsigned int dhi = (unsigned int)(dcur >> 32);

            // scalar-anchored alive mask (uniform -> SALU loop)
            unsigned long long swv = supp[c];
            unsigned long long sw =
                ((unsigned long long)(unsigned int)__builtin_amdgcn_readfirstlane(
                     (int)(unsigned int)(swv >> 32)) << 32) |
                 (unsigned long long)(unsigned int)__builtin_amdgcn_readfirstlane(
                     (int)(unsigned int)swv);
            unsigned long long alive = ~sw;

            // ---- phase A: greedy keeps; readlane crossbar, no LDS in chain ----
            unsigned long long keepw = 0ull;
            while (alive && cnt < MAX_DETS) {
                int t = __ffsll((long long)alive) - 1;     // lowest alive -> kept
                keepw |= (1ull << t);
                ++cnt;
                unsigned long long dt =
                    ((unsigned long long)(unsigned int)__builtin_amdgcn_readlane(
                         (int)dhi, t) << 32) |
                     (unsigned long long)(unsigned int)__builtin_amdgcn_readlane(
                         (int)dlo, t);
                alive &= ~(dt | (1ull << t));
            }
            if (lane == 0) keepw_arr[c] = keepw;

            // ---- phase B: windowed coalesced suppression OR ----
            if (cnt < MAX_DETS && keepw != 0ull) {
                const unsigned long long* rowp = mask + (size_t)(c * 64) * NWORDS;
                for (int wb = c + 1; wb < NC; wb += 64) {
                    int wi = wb + lane;                    // word this lane owns
                    bool act = (wi < NC);
                    unsigned long long acc = 0ull;
                    unsigned long long w = keepw;
                    while (w) {
#define SLOT(i)                                                           \
                        unsigned long long A##i = 0ull;                   \
                        if (w) {                                          \
                            int t = __ffsll((long long)w) - 1;            \
                            w &= w - 1ull;                                \
                            if (act) A##i = rowp[(size_t)t * NWORDS + wi];\
                        }
                        SLOT(0) SLOT(1) SLOT(2) SLOT(3)
                        SLOT(4) SLOT(5) SLOT(6) SLOT(7)
                        SLOT(8) SLOT(9) SLOT(10) SLOT(11)
                        SLOT(12) SLOT(13) SLOT(14) SLOT(15)
#undef SLOT
                        acc |= A0 | A1 | A2 | A3 | A4 | A5 | A6 | A7
                             | A8 | A9 | A10 | A11 | A12 | A13 | A14 | A15;
                    }
                    if (act) supp[wi] |= acc;
                }
            }
        }
    }
    __syncthreads();

    // =================== phase 2: select first K valid =======================
    // valid = keep & ~all(roi==0) & (score>=0.9) & (rescaled area>220).
    // keep bit read via rank[i] (sorted position) against LDS keepw_arr.
    float sy = info[4], sx = info[5];
    int base = 0;
    for (int ch = 0; ch < 16; ++ch) {
        int i = ch * 1024 + tid;
        unsigned int r = rank[i];
        bool keep = ((keepw_arr[r >> 6] >> (r & 63)) & 1ull) != 0ull;
        float4 rb = ((const float4*)roi_boxes)[i];
        bool nz = !((rb.x == 0.0f) && (rb.y == 0.0f) && (rb.z == 0.0f) && (rb.w == 0.0f));
        bool sc = roi_scores[i] >= 0.9f;
        float4 db = ((const float4*)det_boxes)[i];
        float r0 = db.x / sy, r1 = db.y / sx, r2 = db.z / sy, r3 = db.w / sx;
        bool big = ((r2 - r0) * (r3 - r1)) > 220.0f;
        bool valid = keep && nz && sc && big;
        unsigned long long bal = __ballot(valid);
        int wv = tid >> 6, lane = tid & 63;
        if (lane == 0) wcnt[wv] = (int)__popcll(bal);
        __syncthreads();
        int pre = 0, tot = 0;
        for (int w = 0; w < 16; ++w) { int cc = wcnt[w]; tot += cc; if (w < wv) pre += cc; }
        int rk = base + pre + (int)__popcll(bal & ((1ull << lane) - 1ull));
        if (valid && rk < K) idxL[rk] = i;
        base += tot;
        __syncthreads();
    }
    if (tid == 0) countL = base;
    __syncthreads();

    // =================== phase 3: classify + epilogue ========================
    int count = countL;
    int mincount = count < K ? count : K;

    for (int p = tid; p < K * FEAT; p += 1024)
        feat[p] = vis[(size_t)idxL[p >> 9] * FEAT + (p & (FEAT - 1))];
    __syncthreads();

    for (int p = tid; p < K * NUM_CATS; p += 1024) {
        int r = p / NUM_CATS, c = p % NUM_CATS;
        const float* fr = &feat[r * FEAT];
        const float* tr = &tf[(size_t)c * FEAT];
        float s = 0.0f;
#pragma unroll 8
        for (int e = 0; e < FEAT; ++e) s += fr[e] * tr[e];
        scL[p] = s;
    }
    __syncthreads();

    if (tid < K) {
        float mv = scL[tid * NUM_CATS];
        int ma = 0;
        for (int c = 1; c < NUM_CATS; ++c) {
            float v = scL[tid * NUM_CATS + c];
            if (v > mv) { mv = v; ma = c; }     // first-max (jnp.argmax)
        }
        int fg = (tid < mincount) && (ma != 0);
        fgL[tid] = fg;
        keyL[tid] = fg ? mv : -INFINITY;
    }
    __syncthreads();

    if (tid == 0) {                 // stable selection sort, descending
        unsigned used = 0;
        for (int p = 0; p < K; ++p) {
            int bk = -1; float bv = 0.0f;
            for (int k2 = 0; k2 < K; ++k2) {
                if (used & (1u << k2)) continue;
                if (bk < 0 || keyL[k2] > bv) { bk = k2; bv = keyL[k2]; }
            }
            ordL[p] = bk;
            used |= (1u << bk);
        }
    }
    __syncthreads();

    // scores: [0 .. 1599]
    for (int p = tid; p < K * (NUM_CATS - 1); p += 1024) {
        int q = p >> 6, cc = p & 63;
        int src = ordL[q];
        out[p] = fgL[src] ? scL[src * NUM_CATS + cc + 1] : 0.0f;
    }
    // bboxes: [1600 .. 1699]  processed = [xmin, ymin, xmax, ymax]
    for (int p = tid; p < K * 4; p += 1024) {
        int q = p >> 2, e = p & 3;
        int src = ordL[q];
        float v = 0.0f;
        if (fgL[src]) {
            int o = idxL[src];
            float b0 = det_boxes[o * 4 + 0] / sy;   // ymin
            float b1 = det_boxes[o * 4 + 1] / sx;   // xmin
            float b2 = det_boxes[o * 4 + 2] / sy;   // ymax
            float b3 = det_boxes[o * 4 + 3] / sx;   // xmax
            v = (e == 0) ? b1 : (e == 1) ? b0 : (e == 2) ? b3 : b2;
        }
        out[1600 + p] = v;
    }
    // mask: [1700 .. 1724]
    if (tid < K) out[1700 + tid] = fgL[ordL[tid]] ? 1.0f : 0.0f;
}

extern "C" void kernel_launch(void* const* d_in, const int* in_sizes, int n_in,
                              void* d_out, int out_size, void* d_ws, size_t ws_size,
                              hipStream_t stream) {
    const float* roi_boxes  = (const float*)d_in[0];
    const float* roi_scores = (const float*)d_in[1];
    const float* det_boxes  = (const float*)d_in[2];
    // d_in[3] detection_masks: unused by reference
    const float* vis        = (const float*)d_in[4];
    const float* info       = (const float*)d_in[5];
    const float* tf         = (const float*)d_in[6];

    char* ws = (char*)d_ws;
    unsigned long long* keys = (unsigned long long*)(ws + 0);
    unsigned int* rank       = (unsigned int*)(ws + 131072);
    float4* sbox             = (float4*)(ws + 262144);
    float* sarea             = (float*)(ws + 524288);
    unsigned long long* mask = (unsigned long long*)(ws + 589824);
    int* idxArr              = (int*)(ws + 34144256);
    int* ncand_slot          = idxArr + 30;

    k_build<<<64, 256, 0, stream>>>(roi_scores, keys, rank, ncand_slot);
    k_rank<<<dim3(64, 8), 256, 0, stream>>>(keys, roi_scores, rank, ncand_slot);
    k_scatter<<<64, 256, 0, stream>>>(rank, det_boxes, sbox, sarea);
    k_mask<<<1024, 64, 0, stream>>>(sbox, sarea, ncand_slot, mask);
    k_tail<<<1, 1024, 0, stream>>>(mask, rank, ncand_slot, roi_boxes, roi_scores,
                                   det_boxes, info, vis, tf, (float*)d_out);
}

// Round 5
// 395.169 us; speedup vs baseline: 1.4778x; 1.0317x over previous
//
#include <hip/hip_runtime.h>
#include <math.h>

#define N 16384
#define NWORDS 256       // N/64
#define FEAT 512
#define NUM_CATS 65
#define K 25
#define MAX_DETS 1000
#define TB 512           // k_tail block size (8 waves)

// ---------------- ws layout (bytes) ----------------
// keys     : u64[N]            @ 0         (131072)
// rank     : u32[N]            @ 131072    (65536)
// sbox     : float4[N]         @ 262144    (262144)
// sarea    : f32[N]            @ 524288    (65536)
// mask     : u64[N*NWORDS]     @ 589824    (33554432)
// idxArr   : i32[32]           @ 34144256  (128)   [30]=ncand
//
// ncand = #(roi_score >= 0.9). Sort is score-descending; suppression and the
// MAX_DETS counter only flow down the order, and valid requires score>=0.9,
// so the first NC = ceil(ncand/64) sorted chunks fully determine the output.
//
// Scan design (round 5): suppression is a LAZY GATHER. keptList[] holds kept
// sorted-positions; at chunk c, supp_c = OR over kept t of mask[t][c] — all
// loads independent (lane-parallel, 8-wide batches, named regs), then a
// shfl_xor OR-reduce. This replaces the eager per-kept-row scatter whose
// dependent round-trips (exposed by VGPR_Count=24 register starvation at
// 1024 threads) dominated at ~240 µs across four variants.

// Sort key: descending by score, ties -> ascending original index.
__global__ void k_build(const float* __restrict__ scores,
                        unsigned long long* __restrict__ keys,
                        unsigned int* __restrict__ rank,
                        int* __restrict__ ncand_slot) {
    int i = blockIdx.x * 256 + threadIdx.x;
    keys[i] = ((unsigned long long)__float_as_uint(scores[i]) << 32) |
              (unsigned long long)(0xFFFFFFFFu - (unsigned)i);
    rank[i] = 0u;
    if (i == 0) *ncand_slot = 0;   // counted up by k_rank
}

// rank[i] = #{ j : key[j] > key[i] }  (keys distinct -> permutation)
// y==0 slice also counts scores >= 0.9 into ncand_slot (proven pattern).
__global__ void k_rank(const unsigned long long* __restrict__ keys,
                       const float* __restrict__ scores,
                       unsigned int* __restrict__ rank,
                       int* __restrict__ ncand_slot) {
    __shared__ unsigned long long lk[2048];
    int i = blockIdx.x * 256 + threadIdx.x;
    unsigned long long my = keys[i];
    int j0 = blockIdx.y * 2048;
    for (int t = threadIdx.x; t < 2048; t += 256) lk[t] = keys[j0 + t];
    __syncthreads();
    unsigned int cnt = 0;
#pragma unroll 8
    for (int t = 0; t < 2048; ++t) cnt += (lk[t] > my) ? 1u : 0u;
    atomicAdd(&rank[i], cnt);
    if (blockIdx.y == 0) {
        bool hi = scores[i] >= 0.9f;
        unsigned long long bal = __ballot(hi);
        if ((threadIdx.x & 63) == 0)
            atomicAdd(ncand_slot, (int)__popcll(bal));
    }
}

// Scatter boxes into sorted order; precompute areas (exact ref formula).
__global__ void k_scatter(const unsigned int* __restrict__ rank,
                          const float* __restrict__ det_boxes,
                          float4* __restrict__ sbox,
                          float* __restrict__ sarea) {
    int i = blockIdx.x * 256 + threadIdx.x;
    unsigned int r = rank[i];
    float4 b = ((const float4*)det_boxes)[i];   // [y1,x1,y2,x2]
    sbox[r] = b;
    sarea[r] = (b.w - b.y) * (b.z - b.x);       // (x2-x1)*(y2-y1)
}

// Upper-triangular (block-wise) IoU>0.6 bit matrix, candidate chunks only.
// Persistent-tile kernel, fixed 1024-block grid.
__global__ void k_mask(const float4* __restrict__ sbox,
                       const float* __restrict__ sarea,
                       const int* __restrict__ ncand_slot,
                       unsigned long long* __restrict__ mask) {
    int ncand = *ncand_slot;
    if (ncand < 0) ncand = 0;
    if (ncand > N) ncand = N;
    int NC = (ncand + 63) >> 6;
    int total = NC * (NC + 1) / 2;
    __shared__ float4 cbox[64];
    __shared__ float carea[64];
    int t = threadIdx.x;
    for (int tile = blockIdx.x; tile < total; tile += gridDim.x) {
        int cb = (int)((sqrtf(8.0f * (float)tile + 1.0f) - 1.0f) * 0.5f);
        while ((cb + 1) * (cb + 2) / 2 <= tile) ++cb;
        while (cb * (cb + 1) / 2 > tile) --cb;
        int rb = tile - cb * (cb + 1) / 2;

        __syncthreads();                       // protect cbox reuse
        int col0 = cb * 64;
        cbox[t] = sbox[col0 + t];
        carea[t] = sarea[col0 + t];
        __syncthreads();
        int row = rb * 64 + t;
        float4 r = sbox[row];
        float ra = sarea[row];
        unsigned long long bits = 0ull;
        for (int j = 0; j < 64; ++j) {
            int col = col0 + j;
            if (col > row) {
                float4 cbx = cbox[j];
                float iw = fminf(r.w, cbx.w) - fmaxf(r.y, cbx.y);  // x overlap
                iw = fmaxf(iw, 0.0f);
                float ih = fminf(r.z, cbx.z) - fmaxf(r.x, cbx.x);  // y overlap
                ih = fmaxf(ih, 0.0f);
                float inter = iw * ih;
                float iou = inter / (ra + carea[j] - inter + 1e-12f);
                if (iou > 0.6f) bits |= (1ull << j);
            }
        }
        mask[(size_t)row * NWORDS + cb] = bits;
    }
}

// Fused tail: wave 0 runs the greedy scan (lazy-gather suppression); then all
// TB threads do select (via rank[] + LDS keep bits) and classify.
__global__ void __launch_bounds__(TB, 1)
k_tail(const unsigned long long* __restrict__ mask,
       const unsigned int* __restrict__ rank,
       const int* __restrict__ ncand_slot,
       const float* __restrict__ roi_boxes,
       const float* __restrict__ roi_scores,
       const float* __restrict__ det_boxes,
       const float* __restrict__ info,
       const float* __restrict__ vis,
       const float* __restrict__ tf,
       float* __restrict__ out) {
    __shared__ unsigned long long keepw_arr[NWORDS];   // 2 KB
    __shared__ int keptList[1024];                     // 4 KB, kept sorted-pos
    __shared__ float feat[K * FEAT];                   // 50 KB
    __shared__ float scL[K * NUM_CATS];                // 6.5 KB
    __shared__ float keyL[K];
    __shared__ int fgL[K];
    __shared__ int ordL[K];
    __shared__ int idxL[K];
    __shared__ int wcnt[TB / 64];
    __shared__ int countL;
    int tid = threadIdx.x;

    if (tid < K) idxL[tid] = 0;

    // =================== phase 1: greedy NMS scan (wave 0) ===================
    if (tid < 64) {
        int lane = tid;
        for (int i2 = lane; i2 < NWORDS; i2 += 64) keepw_arr[i2] = 0ull;

        int ncand = *ncand_slot;
        if (ncand < 0) ncand = 0;
        if (ncand > N) ncand = N;
        int NC = (ncand + 63) >> 6;

        int cnt = 0;      // uniform: total kept
        int nk = 0;       // uniform: keptList length (== cnt)
        unsigned long long dnext = 0ull;
        if (NC > 0) dnext = mask[(size_t)lane * NWORDS];   // chunk 0 diag word

        for (int c = 0; c < NC; ++c) {
            if (cnt >= MAX_DETS) break;                    // keepw_arr pre-zeroed

            unsigned long long dcur = dnext;               // row lane's diag word
            if (c + 1 < NC)                                // one-ahead prefetch
                dnext = mask[(size_t)((c + 1) * 64 + lane) * NWORDS + (c + 1)];
            unsigned int dlo = (unsigned int)dcur;
            unsigned int dhi = (unsigned int)(dcur >> 32);

            // ---- lazy suppression gather: supp_c = OR over kept t of mask[t][c]
            // lane L handles kept items L, L+64, ... ; 8 independent loads per
            // batch (named regs -> stays in VGPRs, full MLP), <=2 batches.
            unsigned long long acc = 0ull;
            {
                int q = lane;
                while (q < nk) {
#define GS(i)                                                             \
                    unsigned long long G##i = 0ull;                       \
                    {                                                     \
                        int qq = q + 64 * i;                              \
                        if (qq < nk) {                                    \
                            int t = keptList[qq];                         \
                            G##i = mask[(size_t)t * NWORDS + c];          \
                        }                                                 \
                    }
                    GS(0) GS(1) GS(2) GS(3) GS(4) GS(5) GS(6) GS(7)
#undef GS
                    acc |= G0 | G1 | G2 | G3 | G4 | G5 | G6 | G7;
                    q += 512;
                }
            }
            // OR-reduce acc across the wave (butterfly on 32-bit halves)
            unsigned int alo = (unsigned int)acc;
            unsigned int ahi = (unsigned int)(acc >> 32);
            for (int off = 32; off > 0; off >>= 1) {
                alo |= (unsigned int)__shfl_xor((int)alo, off, 64);
                ahi |= (unsigned int)__shfl_xor((int)ahi, off, 64);
            }
            unsigned long long sw =
                ((unsigned long long)(unsigned int)__builtin_amdgcn_readfirstlane(
                     (int)ahi) << 32) |
                 (unsigned long long)(unsigned int)__builtin_amdgcn_readfirstlane(
                     (int)alo);
            unsigned long long alive = ~sw;

            // ---- phase A: greedy keeps; readlane crossbar, scalar-anchored ----
            unsigned long long keepw = 0ull;
            while (alive && cnt < MAX_DETS) {
                int t = __ffsll((long long)alive) - 1;     // lowest alive -> kept
                keepw |= (1ull << t);
                ++cnt;
                unsigned long long dt =
                    ((unsigned long long)(unsigned int)__builtin_amdgcn_readlane(
                         (int)dhi, t) << 32) |
                     (unsigned long long)(unsigned int)__builtin_amdgcn_readlane(
                         (int)dlo, t);
                alive &= ~(dt | (1ull << t));
            }
            if (lane == 0) keepw_arr[c] = keepw;

            // ---- append kept positions to keptList (lane-parallel) ----
            if (keepw != 0ull) {
                if ((keepw >> lane) & 1ull) {
                    int pre = (int)__popcll(keepw & ((1ull << lane) - 1ull));
                    keptList[nk + pre] = c * 64 + lane;
                }
                nk += (int)__popcll(keepw);
            }
        }
    }
    __syncthreads();

    // =================== phase 2: select first K valid =======================
    // valid = keep & ~all(roi==0) & (score>=0.9) & (rescaled area>220).
    // keep bit read via rank[i] (sorted position) against LDS keepw_arr.
    float sy = info[4], sx = info[5];
    int base = 0;
    for (int ch = 0; ch < N / TB; ++ch) {
        int i = ch * TB + tid;
        unsigned int r = rank[i];
        bool keep = ((keepw_arr[r >> 6] >> (r & 63)) & 1ull) != 0ull;
        float4 rb = ((const float4*)roi_boxes)[i];
        bool nz = !((rb.x == 0.0f) && (rb.y == 0.0f) && (rb.z == 0.0f) && (rb.w == 0.0f));
        bool sc = roi_scores[i] >= 0.9f;
        float4 db = ((const float4*)det_boxes)[i];
        float r0 = db.x / sy, r1 = db.y / sx, r2 = db.z / sy, r3 = db.w / sx;
        bool big = ((r2 - r0) * (r3 - r1)) > 220.0f;
        bool valid = keep && nz && sc && big;
        unsigned long long bal = __ballot(valid);
        int wv = tid >> 6, lane = tid & 63;
        if (lane == 0) wcnt[wv] = (int)__popcll(bal);
        __syncthreads();
        int pre = 0, tot = 0;
        for (int w = 0; w < TB / 64; ++w) { int cc = wcnt[w]; tot += cc; if (w < wv) pre += cc; }
        int rk = base + pre + (int)__popcll(bal & ((1ull << lane) - 1ull));
        if (valid && rk < K) idxL[rk] = i;
        base += tot;
        __syncthreads();
    }
    if (tid == 0) countL = base;
    __syncthreads();

    // =================== phase 3: classify + epilogue ========================
    int count = countL;
    int mincount = count < K ? count : K;

    for (int p = tid; p < K * FEAT; p += TB)
        feat[p] = vis[(size_t)idxL[p >> 9] * FEAT + (p & (FEAT - 1))];
    __syncthreads();

    for (int p = tid; p < K * NUM_CATS; p += TB) {
        int r = p / NUM_CATS, c = p % NUM_CATS;
        const float* fr = &feat[r * FEAT];
        const float* tr = &tf[(size_t)c * FEAT];
        float s = 0.0f;
#pragma unroll 8
        for (int e = 0; e < FEAT; ++e) s += fr[e] * tr[e];
        scL[p] = s;
    }
    __syncthreads();

    if (tid < K) {
        float mv = scL[tid * NUM_CATS];
        int ma = 0;
        for (int c = 1; c < NUM_CATS; ++c) {
            float v = scL[tid * NUM_CATS + c];
            if (v > mv) { mv = v; ma = c; }     // first-max (jnp.argmax)
        }
        int fg = (tid < mincount) && (ma != 0);
        fgL[tid] = fg;
        keyL[tid] = fg ? mv : -INFINITY;
    }
    __syncthreads();

    if (tid == 0) {                 // stable selection sort, descending
        unsigned used = 0;
        for (int p = 0; p < K; ++p) {
            int bk = -1; float bv = 0.0f;
            for (int k2 = 0; k2 < K; ++k2) {
                if (used & (1u << k2)) continue;
                if (bk < 0 || keyL[k2] > bv) { bk = k2; bv = keyL[k2]; }
            }
            ordL[p] = bk;
            used |= (1u << bk);
        }
    }
    __syncthreads();

    // scores: [0 .. 1599]
    for (int p = tid; p < K * (NUM_CATS - 1); p += TB) {
        int q = p >> 6, cc = p & 63;
        int src = ordL[q];
        out[p] = fgL[src] ? scL[src * NUM_CATS + cc + 1] : 0.0f;
    }
    // bboxes: [1600 .. 1699]  processed = [xmin, ymin, xmax, ymax]
    for (int p = tid; p < K * 4; p += TB) {
        int q = p >> 2, e = p & 3;
        int src = ordL[q];
        float v = 0.0f;
        if (fgL[src]) {
            int o = idxL[src];
            float b0 = det_boxes[o * 4 + 0] / sy;   // ymin
            float b1 = det_boxes[o * 4 + 1] / sx;   // xmin
            float b2 = det_boxes[o * 4 + 2] / sy;   // ymax
            float b3 = det_boxes[o * 4 + 3] / sx;   // xmax
            v = (e == 0) ? b1 : (e == 1) ? b0 : (e == 2) ? b3 : b2;
        }
        out[1600 + p] = v;
    }
    // mask: [1700 .. 1724]
    if (tid < K) out[1700 + tid] = fgL[ordL[tid]] ? 1.0f : 0.0f;
}

extern "C" void kernel_launch(void* const* d_in, const int* in_sizes, int n_in,
                              void* d_out, int out_size, void* d_ws, size_t ws_size,
                              hipStream_t stream) {
    const float* roi_boxes  = (const float*)d_in[0];
    const float* roi_scores = (const float*)d_in[1];
    const float* det_boxes  = (const float*)d_in[2];
    // d_in[3] detection_masks: unused by reference
    const float* vis        = (const float*)d_in[4];
    const float* info       = (const float*)d_in[5];
    const float* tf         = (const float*)d_in[6];

    char* ws = (char*)d_ws;
    unsigned long long* keys = (unsigned long long*)(ws + 0);
    unsigned int* rank       = (unsigned int*)(ws + 131072);
    float4* sbox             = (float4*)(ws + 262144);
    float* sarea             = (float*)(ws + 524288);
    unsigned long long* mask = (unsigned long long*)(ws + 589824);
    int* idxArr              = (int*)(ws + 34144256);
    int* ncand_slot          = idxArr + 30;

    k_build<<<64, 256, 0, stream>>>(roi_scores, keys, rank, ncand_slot);
    k_rank<<<dim3(64, 8), 256, 0, stream>>>(keys, roi_scores, rank, ncand_slot);
    k_scatter<<<64, 256, 0, stream>>>(rank, det_boxes, sbox, sarea);
    k_mask<<<1024, 64, 0, stream>>>(sbox, sarea, ncand_slot, mask);
    k_tail<<<1, TB, 0, stream>>>(mask, rank, ncand_slot, roi_boxes, roi_scores,
                                 det_boxes, info, vis, tf, (float*)d_out);
}